// Round 12
// baseline (184.555 us; speedup 1.0000x reference)
//
#include <hip/hip_runtime.h>

#define BATCH 4
#define SEQQ  2048
#define SEQKV 2048
#define NH    4      // kv heads (effective q heads after group-sum over g)
#define HD    64
#define IND   1024
// 0.125 (1/sqrt(64)) * log2(e): folded into Qr so softmax runs in exp2 domain
#define QSCL 0.18033688011112042f

typedef __attribute__((ext_vector_type(8))) short short8;   // 8 x bf16 raw bits
typedef __attribute__((ext_vector_type(4))) short s4v;      // 4 x bf16 raw bits
typedef __attribute__((ext_vector_type(4))) float floatx4;  // MFMA accum

#if defined(__HIP_DEVICE_COMPILE__) && __has_builtin(__builtin_amdgcn_exp2f)
  #define EXP2(x) __builtin_amdgcn_exp2f(x)
#else
  #define EXP2(x) exp2f(x)
#endif

#define MFMA32(a, b, c) __builtin_amdgcn_mfma_f32_16x16x32_bf16(a, b, c, 0, 0, 0)

__device__ __forceinline__ short f2b(float f) {             // RNE
    unsigned u; __builtin_memcpy(&u, &f, 4);
    u = (u + 0x7fffu + ((u >> 16) & 1u)) >> 16;
    return (short)u;
}
__device__ __forceinline__ short8 cvt8(const float* p) {
    float4 a = *(const float4*)p;
    float4 b = *(const float4*)(p + 4);
    short8 r;
    r[0] = f2b(a.x); r[1] = f2b(a.y); r[2] = f2b(a.z); r[3] = f2b(a.w);
    r[4] = f2b(b.x); r[5] = f2b(b.y); r[6] = f2b(b.z); r[7] = f2b(b.w);
    return r;
}

// ---------------------------------------------------------------------------
// prep_all: LDS-tiled coalesced weight transposes + q/kv fp32->bf16.
// Grid 4352 x 256 (256 weight blocks + 2048 q-cvt + 2048 kv-cvt, 16 elem/thr).
__global__ __launch_bounds__(256) void prep_all(
    const float* __restrict__ Wq, const float* __restrict__ Wk,
    const float* __restrict__ Wv, const float* __restrict__ Wo,
    const float* __restrict__ q, const float* __restrict__ kv,
    short* __restrict__ Wq_t, short* __restrict__ Wkv_t, short* __restrict__ Wo_t,
    short* __restrict__ qb, short* __restrict__ kvb) {
    __shared__ short Ts[64][65];
    int blk = blockIdx.x;
    if (blk < 256) {
        int c4 = threadIdx.x & 63, r4 = threadIdx.x >> 6;
        if (blk < 64) {                       // Wq (group-sum over g)
            int h = blk & 3, ib = blk >> 2;
#pragma unroll 4
            for (int jj = 0; jj < 16; ++jj) {
                int il = r4 * 16 + jj;
                float s = 0.f;
#pragma unroll
                for (int g = 0; g < 4; ++g)
                    s += Wq[(ib * 64 + il) * 1024 + (h * 4 + g) * 64 + c4];
                Ts[il][c4] = f2b(s);
            }
            __syncthreads();
#pragma unroll 4
            for (int jj = 0; jj < 16; ++jj) {
                int dl = r4 * 16 + jj;
                Wq_t[(h * 64 + dl) * 1024 + ib * 64 + c4] = Ts[c4][dl];
            }
        } else if (blk < 192) {               // Wk / Wv
            int t = blk - 64, ss = t >> 6; t &= 63;
            int ib = t >> 2, nb = t & 3;
            const float* W = ss ? Wv : Wk;
#pragma unroll 4
            for (int jj = 0; jj < 16; ++jj) {
                int il = r4 * 16 + jj;
                Ts[il][c4] = f2b(W[(ib * 64 + il) * 256 + nb * 64 + c4]);
            }
            __syncthreads();
#pragma unroll 4
            for (int jj = 0; jj < 16; ++jj) {
                int dl = r4 * 16 + jj;
                Wkv_t[(ss * 256 + nb * 64 + dl) * 1024 + ib * 64 + c4] = Ts[c4][dl];
            }
        } else {                              // Wo
            int t = blk - 192, kb = t >> 4, nb = t & 15;
#pragma unroll 4
            for (int jj = 0; jj < 16; ++jj) {
                int il = r4 * 16 + jj;
                Ts[il][c4] = f2b(Wo[(kb * 64 + il) * 1024 + nb * 64 + c4]);
            }
            __syncthreads();
#pragma unroll 4
            for (int jj = 0; jj < 16; ++jj) {
                int dl = r4 * 16 + jj;
                Wo_t[(nb * 64 + dl) * 256 + kb * 64 + c4] = Ts[c4][dl];
            }
        }
    } else if (blk < 2304) {
        long e = ((long)(blk - 256) * 256 + threadIdx.x) * 16;
        *(short8*)(qb + e)     = cvt8(q + e);
        *(short8*)(qb + e + 8) = cvt8(q + e + 8);
    } else {
        long e = ((long)(blk - 2304) * 256 + threadIdx.x) * 16;
        *(short8*)(kvb + e)     = cvt8(kv + e);
        *(short8*)(kvb + e + 8) = cvt8(kv + e + 8);
    }
}

// ---------------------------------------------------------------------------
// Projection GEMM, 128x64 tile, BK=64 (16 K-steps), now TRIPLE-buffered with
// COUNTED vmcnt (T4): prologue stages tiles 0,1; each iter waits vmcnt(6)
// (own tile-t loads done, tile-t+1's 6 stay IN FLIGHT across the barrier),
// raw s_barrier, then stages tile t+2 and computes tile t. Drain-to-0 only
// on the last iteration. Hazards: stage(t+2) overwrites buf[(t-1)%3], whose
// readers all passed this barrier (ds_reads retired via lgkmcnt before their
// MFMAs); WAW on that buf cleared by iter t-1's vmcnt. 72 KB LDS -> 2
// blocks/CU. XOR-chunk-swizzled LDS (rule-21 both-sides); chunked XCD
// swizzle for L2 reuse.
template <int MODE>
__device__ __forceinline__ void gemm64(
    const short* __restrict__ A, const short* __restrict__ Wt,
    int m0, int n0, short* As, short* Bs,
    const int* __restrict__ coords, short* __restrict__ ropeDst,
    short* __restrict__ vDst) {
    const int t = threadIdx.x;
    const int w = t >> 6, lane = t & 63, ln = lane & 15, quad = lane >> 4;
    const int srow8 = lane >> 3;                    // 8 rows per inst
    const int schk = (lane & 7) ^ (srow8 & 7);      // pre-swizzled 16B chunk
    const int ln7 = ln & 7;
    floatx4 acc[2][4];
#pragma unroll
    for (int mt = 0; mt < 2; ++mt)
#pragma unroll
        for (int nt = 0; nt < 4; ++nt) acc[mt][nt] = floatx4{0.f, 0.f, 0.f, 0.f};

    auto stage = [&](int ks, int sel) {             // 6 loads per wave
#pragma unroll
        for (int i = 0; i < 4; ++i)               // A: 128 rows (wave: 32)
            __builtin_amdgcn_global_load_lds(
                (const void*)(A + (long)(m0 + w * 32 + i * 8 + srow8) * 1024 + ks + schk * 8),
                (void*)(As + sel * 8192 + (w * 32 + i * 8) * 64), 16, 0, 0);
#pragma unroll
        for (int i = 0; i < 2; ++i)               // B: 64 rows (wave: 16)
            __builtin_amdgcn_global_load_lds(
                (const void*)(Wt + (long)(n0 + w * 16 + i * 8 + srow8) * 1024 + ks + schk * 8),
                (void*)(Bs + sel * 4096 + (w * 16 + i * 8) * 64), 16, 0, 0);
    };

    stage(0, 0);
    stage(64, 1);                              // 12 loads in flight
    for (int tt = 0; tt < 16; ++tt) {
        if (tt < 15) asm volatile("s_waitcnt vmcnt(6)" ::: "memory");
        else         asm volatile("s_waitcnt vmcnt(0)" ::: "memory");
        __builtin_amdgcn_s_barrier();          // tile tt fully in LDS, all waves
        if (tt + 2 < 16) stage((tt + 2) * 64, (tt + 2) % 3);
        const short* Ac = As + (tt % 3) * 8192;
        const short* Bc = Bs + (tt % 3) * 4096;
        short8 af[2][2], bf[4][2];
#pragma unroll
        for (int mt = 0; mt < 2; ++mt)
#pragma unroll
            for (int kc = 0; kc < 2; ++kc)
                af[mt][kc] = *(const short8*)(Ac + (w * 32 + mt * 16 + ln) * 64
                                              + ((kc * 4 + quad) ^ ln7) * 8);
#pragma unroll
        for (int nt = 0; nt < 4; ++nt)
#pragma unroll
            for (int kc = 0; kc < 2; ++kc)
                bf[nt][kc] = *(const short8*)(Bc + (nt * 16 + ln) * 64
                                              + ((kc * 4 + quad) ^ ln7) * 8);
#pragma unroll
        for (int kc = 0; kc < 2; ++kc)
#pragma unroll
            for (int mt = 0; mt < 2; ++mt)
#pragma unroll
                for (int nt = 0; nt < 4; ++nt)
                    acc[mt][nt] = MFMA32(af[mt][kc], bf[nt][kc], acc[mt][nt]);
    }

    if (MODE == 1 || n0 < 256) {              // ---- rope path (Q or K)
        const int h = (n0 >> 6) & 3;
        const float scl = (MODE == 1) ? QSCL : 1.0f;
        const float L = -0.5756462732485114f; // -ln(1e4)/16
        const float fA = __expf((float)(ln >> 1) * L);
        const float fB = __expf((float)(8 + (ln >> 1)) * L);
        const float sgn = (ln & 1) ? 1.0f : -1.0f;
#pragma unroll
        for (int mt = 0; mt < 2; ++mt) {
            int row0 = m0 + w * 32 + mt * 16 + quad * 4;
#pragma unroll
            for (int r = 0; r < 4; ++r) {
                int row = row0 + r;
                float c0 = (float)coords[row * 2];
                float c1 = (float)coords[row * 2 + 1];
                float snv[4], csv[4];
                __sincosf(c0 * fA, &snv[0], &csv[0]);   // nt=0: axis0, j=ln>>1
                __sincosf(c0 * fB, &snv[1], &csv[1]);   // nt=1: axis0, j=8+ln>>1
                __sincosf(c1 * fA, &snv[2], &csv[2]);   // nt=2: axis1
                __sincosf(c1 * fB, &snv[3], &csv[3]);   // nt=3: axis1
                long rbase = ((long)((row >> 11) * 4 + h) * 2048 + (row & 2047)) * 64;
#pragma unroll
                for (int nt = 0; nt < 4; ++nt) {
                    float v = acc[mt][nt][r];
                    float p = __shfl_xor(v, 1, 64);     // pair partner (dd^1)
                    float o = v * (csv[nt] * scl) + p * (snv[nt] * (scl * sgn));
                    ropeDst[rbase + nt * 16 + ln] = f2b(o);
                }
            }
        }
    } else {                                  // ---- V transpose path
        const int h = ((n0 - 256) >> 6) & 3;
#pragma unroll
        for (int mt = 0; mt < 2; ++mt) {
            int row0 = m0 + w * 32 + mt * 16 + quad * 4;
            int b = row0 >> 11, s0 = row0 & 2047;
#pragma unroll
            for (int nt = 0; nt < 4; ++nt) {
                s4v ov;                       // 4 consecutive s per lane
#pragma unroll
                for (int r = 0; r < 4; ++r) ov[r] = f2b(acc[mt][nt][r]);
                *(s4v*)(vDst + (long)((b * 4 + h) * 64 + nt * 16 + ln) * 2048 + s0) = ov;
            }
        }
    }
}

__global__ __launch_bounds__(256, 2) void proj_gemm(
    const short* __restrict__ qb, const short* __restrict__ kvb,
    const short* __restrict__ Wq_t, const short* __restrict__ Wkv_t,
    const int* __restrict__ qc, const int* __restrict__ kvc,
    short* __restrict__ Qr, short* __restrict__ Kr, short* __restrict__ Vt) {
    __shared__ __align__(16) short As[3 * 8192];   // 48 KB A tri-buf (128x64)
    __shared__ __align__(16) short Bs[3 * 4096];   // 24 KB B tri-buf (64x64)
    // chunked XCD swizzle (768 = 8 x 96, bijective)
    int id = (blockIdx.x & 7) * 96 + (blockIdx.x >> 3);
    if (id < 256)
        gemm64<1>(qb, Wq_t, (id >> 2) * 128, (id & 3) * 64, As, Bs, qc, Qr, nullptr);
    else {
        int t2 = id - 256;
        gemm64<2>(kvb, Wkv_t, (t2 >> 3) * 128, (t2 & 7) * 64, As, Bs, kvc, Kr, Vt);
    }
}

// ---------------------------------------------------------------------------
// final GEMM: C[M][N] f32 = Ob[M][K] bf16 x Wo_t[N][K] bf16, 128x128 tile,
// BK=64 (4 K-steps), XOR-chunk-swizzled LDS. (R9, unchanged.)
__global__ __launch_bounds__(256, 2) void final_gemm(
    const short* __restrict__ Ob, const short* __restrict__ Wo_t, float* __restrict__ out) {
    __shared__ __align__(16) short As[2 * 8192];   // 32 KB (128x64)
    __shared__ __align__(16) short Bs[2 * 8192];   // 32 KB (128x64)
    const int m0 = blockIdx.x * 128, n0 = blockIdx.y * 128;
    const int tid = threadIdx.x;
    const int w = tid >> 6, lane = tid & 63, ln = lane & 15, quad = lane >> 4;
    const int wm = w >> 1, wn = w & 1;
    const int srow8 = lane >> 3;
    const int schk = (lane & 7) ^ (srow8 & 7);
    const int ln7 = ln & 7;
    floatx4 acc[4][4];
#pragma unroll
    for (int mt = 0; mt < 4; ++mt)
#pragma unroll
        for (int nt = 0; nt < 4; ++nt) acc[mt][nt] = floatx4{0.f, 0.f, 0.f, 0.f};

    auto stage = [&](int ks, int sel) {
#pragma unroll
        for (int i = 0; i < 4; ++i) {             // 128 rows each (wave: 32)
            __builtin_amdgcn_global_load_lds(
                (const void*)(Ob + (long)(m0 + w * 32 + i * 8 + srow8) * 256 + ks + schk * 8),
                (void*)(As + sel * 8192 + (w * 32 + i * 8) * 64), 16, 0, 0);
            __builtin_amdgcn_global_load_lds(
                (const void*)(Wo_t + (long)(n0 + w * 32 + i * 8 + srow8) * 256 + ks + schk * 8),
                (void*)(Bs + sel * 8192 + (w * 32 + i * 8) * 64), 16, 0, 0);
        }
    };
    stage(0, 0);
    __syncthreads();
    int cur = 0;
    for (int tt = 0; tt < 4; ++tt) {
        if (tt < 3) stage((tt + 1) * 64, cur ^ 1);
        const short* Ac = As + cur * 8192;
        const short* Bc = Bs + cur * 8192;
        short8 af[4][2], bf[4][2];
#pragma unroll
        for (int mt = 0; mt < 4; ++mt)
#pragma unroll
            for (int kc = 0; kc < 2; ++kc)
                af[mt][kc] = *(const short8*)(Ac + (wm * 64 + mt * 16 + ln) * 64
                                              + ((kc * 4 + quad) ^ ln7) * 8);
#pragma unroll
        for (int nt = 0; nt < 4; ++nt)
#pragma unroll
            for (int kc = 0; kc < 2; ++kc)
                bf[nt][kc] = *(const short8*)(Bc + (wn * 64 + nt * 16 + ln) * 64
                                              + ((kc * 4 + quad) ^ ln7) * 8);
#pragma unroll
        for (int kc = 0; kc < 2; ++kc)
#pragma unroll
            for (int mt = 0; mt < 4; ++mt)
#pragma unroll
                for (int nt = 0; nt < 4; ++nt)
                    acc[mt][nt] = MFMA32(af[mt][kc], bf[nt][kc], acc[mt][nt]);
        __syncthreads();
        cur ^= 1;
    }
#pragma unroll
    for (int mt = 0; mt < 4; ++mt) {
        int row0 = m0 + wm * 64 + mt * 16 + quad * 4;
#pragma unroll
        for (int nt = 0; nt < 4; ++nt) {
            int col = n0 + wn * 64 + nt * 16 + ln;
#pragma unroll
            for (int r = 0; r < 4; ++r)
                out[(long)(row0 + r) * 1024 + col] = acc[mt][nt][r];
        }
    }
}

// ---------------------------------------------------------------------------
// Flash attention, IN-BLOCK kv-split-2 (R6/R9 8-wave structure) with
// PAIRED-T MFMA32 PV (R11, unchanged).
__global__ __launch_bounds__(512, 4) void attn_kernel(
    const short* __restrict__ Qr, const short* __restrict__ Kr,
    const short* __restrict__ Vt, short* __restrict__ Ob) {
    __shared__ __align__(16) short Kls[2][2][64 * 64];   // [half][buf][kv][d]
    __shared__ __align__(16) short Vls[2][2][64 * 64];   // [half][buf][d][kv]
    const int blk = blockIdx.x;
    const int x = blk & 7, y = blk >> 3;              // xcd-chunk swizzle
    const int bh = x * 2 + (y >> 5), qg = y & 31;
    const int w = threadIdx.x >> 6, lane = threadIdx.x & 63;
    const int qw = w & 3, half = w >> 2;
    const int ln = lane & 15, quad = lane >> 4;
    const int q0 = qg * 64 + qw * 16;
    const short* Qb = Qr + (long)bh * SEQKV * HD;
    const short* Kb = Kr + (long)bh * SEQKV * HD + (long)half * 1024 * HD;
    const short* Vb = Vt + (long)bh * HD * SEQKV + half * 1024;

    const int srow = lane >> 3;                       // 0..7 within 8-row group
    const int schk = (lane & 7) ^ (srow & 7);         // swizzled 16B chunk
    const long kstage0 = (long)(qw * 16 + srow) * HD + schk * 8;        // + kt*HD
    const long vstage0 = (long)(qw * 16 + srow) * SEQKV + schk * 8;     // + kt

    short8 qf[2];                              // B-frag of Q^T: [d-chunk32]
#pragma unroll
    for (int ck = 0; ck < 2; ++ck)
        qf[ck] = *(const short8*)(Qb + (long)(q0 + ln) * HD + ck * 32 + quad * 8);

    short8 ones8;
#pragma unroll
    for (int j = 0; j < 8; ++j) ones8[j] = (short)0x3F80;   // bf16 1.0

    floatx4 o[4], ol;
    ol = floatx4{0.f, 0.f, 0.f, 0.f};
#pragma unroll
    for (int nt = 0; nt < 4; ++nt) o[nt] = floatx4{0.f, 0.f, 0.f, 0.f};

    const int ln7 = ln & 7;
    int koff[2];
#pragma unroll
    for (int ck = 0; ck < 2; ++ck) koff[ck] = ln * 64 + ((ck * 4 + quad) ^ ln7) * 8;
    int voff[4];
#pragma unroll
    for (int t = 0; t < 4; ++t) voff[t] = ln * 64 + ((t * 2 + (quad >> 1)) ^ ln7) * 8 + (quad & 1) * 4;

#define STAGE(kt, sel)                                                                \
    do {                                                                              \
        _Pragma("unroll")                                                             \
        for (int i = 0; i < 2; ++i) {                                                 \
            __builtin_amdgcn_global_load_lds(                                         \
                (const void*)(Kb + (long)(kt) * HD + kstage0 + (long)i * 8 * HD),     \
                (void*)(&Kls[half][sel][(qw * 16 + i * 8) * 64]), 16, 0, 0);          \
            __builtin_amdgcn_global_load_lds(                                         \
                (const void*)(Vb + (kt) + vstage0 + (long)i * 8 * SEQKV),             \
                (void*)(&Vls[half][sel][(qw * 16 + i * 8) * 64]), 16, 0, 0);          \
        }                                                                             \
    } while (0)

    STAGE(0, 0);
    __syncthreads();
    int cur = 0;
    for (int tt = 0; tt < 16; ++tt) {
        if (tt < 15) STAGE((tt + 1) * 64, cur ^ 1);
        const short* Kc = &Kls[half][cur][0];
        const short* Vc = &Vls[half][cur][0];
#pragma unroll
        for (int t2 = 0; t2 < 2; ++t2) {
            const int ta = t2 * 2, tb = ta + 1;
            short8 a0a = *(const short8*)(Kc + ta * 1024 + koff[0]);
            short8 a1a = *(const short8*)(Kc + ta * 1024 + koff[1]);
            short8 a0b = *(const short8*)(Kc + tb * 1024 + koff[0]);
            short8 a1b = *(const short8*)(Kc + tb * 1024 + koff[1]);
            floatx4 sta = {0.f, 0.f, 0.f, 0.f}, stb = {0.f, 0.f, 0.f, 0.f};
            __builtin_amdgcn_s_setprio(1);
            sta = MFMA32(a0a, qf[0], sta);
            stb = MFMA32(a0b, qf[0], stb);
            sta = MFMA32(a1a, qf[1], sta);
            stb = MFMA32(a1b, qf[1], stb);
            __builtin_amdgcn_s_setprio(0);
            float e0 = EXP2(sta[0]), e1 = EXP2(sta[1]), e2 = EXP2(sta[2]), e3 = EXP2(sta[3]);
            float g0 = EXP2(stb[0]), g1 = EXP2(stb[1]), g2 = EXP2(stb[2]), g3 = EXP2(stb[3]);
            unsigned p0, p1, p2, p3;
            asm("v_cvt_pk_bf16_f32 %0, %1, %2" : "=v"(p0) : "v"(e0), "v"(e1));
            asm("v_cvt_pk_bf16_f32 %0, %1, %2" : "=v"(p1) : "v"(e2), "v"(e3));
            asm("v_cvt_pk_bf16_f32 %0, %1, %2" : "=v"(p2) : "v"(g0), "v"(g1));
            asm("v_cvt_pk_bf16_f32 %0, %1, %2" : "=v"(p3) : "v"(g2), "v"(g3));
            short8 pt8;                        // K=32 B-frag: [pt(ta)|pt(tb)]
            { unsigned tmp[4] = {p0, p1, p2, p3}; __builtin_memcpy(&pt8, tmp, 16); }
            __builtin_amdgcn_s_setprio(1);
#pragma unroll
            for (int nt = 0; nt < 4; ++nt) {   // O^T += V^T P^T, K=32
                s4v vfa = *(const s4v*)(Vc + nt * 1024 + voff[ta]);
                s4v vfb = *(const s4v*)(Vc + nt * 1024 + voff[tb]);
                short8 vf8;
                __builtin_memcpy(&vf8, &vfa, 8);
                __builtin_memcpy((short*)&vf8 + 4, &vfb, 8);
                o[nt] = MFMA32(vf8, pt8, o[nt]);
            }
            ol = MFMA32(ones8, pt8, ol);       // l += 1^T P^T, K=32
            __builtin_amdgcn_s_setprio(0);
        }
        __syncthreads();                       // drains prefetch vmcnt + barrier
        cur ^= 1;
    }
#undef STAGE
    // in-block combine (last loop barrier guarantees all LDS reads done):
    // half 1 publishes O (16 f32) + l per lane into Kls-scratch, half 0 reduces.
    float* cb = (float*)&Kls[0][0][0];             // 20 KB scratch, 16B-aligned slots
    const int slot = (qw * 64 + lane) * 20;        // 80 B stride (16B-multiple)
    if (half == 1) {
#pragma unroll
        for (int nt = 0; nt < 4; ++nt)
            *(floatx4*)(cb + slot + nt * 4) = o[nt];
        cb[slot + 16] = ol[0];
    }
    __syncthreads();
    if (half == 0) {
        const int b = bh >> 2, h = bh & 3;
        const float li = 1.0f / (ol[0] + cb[slot + 16]);
        const long base = ((long)(b * 2048 + q0 + ln)) * 256 + h * 64;
#pragma unroll
        for (int nt = 0; nt < 4; ++nt) {
            floatx4 o2 = *(const floatx4*)(cb + slot + nt * 4);
            s4v ov;
#pragma unroll
            for (int r = 0; r < 4; ++r) ov[r] = f2b((o[nt][r] + o2[r]) * li);
            *(s4v*)(Ob + base + nt * 16 + quad * 4) = ov;
        }
    }
}

// ---------------------------------------------------------------------------
extern "C" void kernel_launch(void* const* d_in, const int* in_sizes, int n_in,
                              void* d_out, int out_size, void* d_ws, size_t ws_size,
                              hipStream_t stream) {
    const float* q   = (const float*)d_in[0];
    const int*   qc  = (const int*)d_in[1];
    const float* kv  = (const float*)d_in[2];
    const int*   kvc = (const int*)d_in[3];
    const float* Wq  = (const float*)d_in[4];
    const float* Wk  = (const float*)d_in[5];
    const float* Wv  = (const float*)d_in[6];
    const float* Wo  = (const float*)d_in[7];
    float* out = (float*)d_out;

    char* ws = (char*)d_ws;
    const size_t MB = 1024 * 1024;
    short* Wq_t  = (short*)(ws);                 // 0.5 MB  [256][1024]
    short* Wkv_t = (short*)(ws + MB / 2);        // 1.0 MB  [512][1024]
    short* Wo_t  = (short*)(ws + 3 * MB / 2);    // 0.5 MB  [1024][256]
    short* qb    = (short*)(ws + 2 * MB);        // 16 MB   [8192][1024] bf16
    short* kvb   = (short*)(ws + 18 * MB);       // 16 MB
    short* Qr    = (short*)(ws + 34 * MB);       // 4 MB  [16][2048][64]
    short* Kr    = (short*)(ws + 38 * MB);       // 4 MB
    short* Vt    = (short*)(ws + 42 * MB);       // 4 MB  [16][64][2048]
    short* Ob    = (short*)(ws + 46 * MB);       // 4 MB  [8192][256]

    hipLaunchKernelGGL(prep_all, dim3(4352), dim3(256), 0, stream,
                       Wq, Wk, Wv, Wo, q, kv, Wq_t, Wkv_t, Wo_t, qb, kvb);
    hipLaunchKernelGGL(proj_gemm, dim3(768), dim3(256), 0, stream,
                       qb, kvb, Wq_t, Wkv_t, qc, kvc, Qr, Kr, Vt);
    hipLaunchKernelGGL(attn_kernel, dim3(512), dim3(512), 0, stream,
                       Qr, Kr, Vt, Ob);
    hipLaunchKernelGGL(final_gemm, dim3(64, 8), dim3(256), 0, stream, Ob, Wo_t, out);
}

// Round 13
// 177.803 us; speedup vs baseline: 1.0380x; 1.0380x over previous
//
#include <hip/hip_runtime.h>

#define BATCH 4
#define SEQQ  2048
#define SEQKV 2048
#define NH    4      // kv heads (effective q heads after group-sum over g)
#define HD    64
#define IND   1024
// 0.125 (1/sqrt(64)) * log2(e): folded into Qr so softmax runs in exp2 domain
#define QSCL 0.18033688011112042f

typedef __attribute__((ext_vector_type(8))) short short8;   // 8 x bf16 raw bits
typedef __attribute__((ext_vector_type(4))) short s4v;      // 4 x bf16 raw bits
typedef __attribute__((ext_vector_type(4))) float floatx4;  // MFMA accum

#if defined(__HIP_DEVICE_COMPILE__) && __has_builtin(__builtin_amdgcn_exp2f)
  #define EXP2(x) __builtin_amdgcn_exp2f(x)
#else
  #define EXP2(x) exp2f(x)
#endif

#if defined(__HIP_DEVICE_COMPILE__)
  #if __has_builtin(__builtin_amdgcn_mfma_f32_16x16x16bf16_1k)
    #define MFMA16(a, b, c) __builtin_amdgcn_mfma_f32_16x16x16bf16_1k(a, b, c, 0, 0, 0)
  #elif __has_builtin(__builtin_amdgcn_mfma_f32_16x16x16_bf16)
    #define MFMA16(a, b, c) __builtin_amdgcn_mfma_f32_16x16x16_bf16(a, b, c, 0, 0, 0)
  #else
    #error "no 16x16x16 bf16 MFMA builtin on gfx950 device pass"
  #endif
#else
  #define MFMA16(a, b, c) (c)   // host pass placeholder, never executed
#endif
#define MFMA32(a, b, c) __builtin_amdgcn_mfma_f32_16x16x32_bf16(a, b, c, 0, 0, 0)

__device__ __forceinline__ short f2b(float f) {             // RNE
    unsigned u; __builtin_memcpy(&u, &f, 4);
    u = (u + 0x7fffu + ((u >> 16) & 1u)) >> 16;
    return (short)u;
}
__device__ __forceinline__ short8 cvt8(const float* p) {
    float4 a = *(const float4*)p;
    float4 b = *(const float4*)(p + 4);
    short8 r;
    r[0] = f2b(a.x); r[1] = f2b(a.y); r[2] = f2b(a.z); r[3] = f2b(a.w);
    r[4] = f2b(b.x); r[5] = f2b(b.y); r[6] = f2b(b.z); r[7] = f2b(b.w);
    return r;
}

// ---------------------------------------------------------------------------
// prep_all: LDS-tiled coalesced weight transposes + q/kv fp32->bf16.
// Grid 4352 x 256 (256 weight blocks + 2048 q-cvt + 2048 kv-cvt, 16 elem/thr).
__global__ __launch_bounds__(256) void prep_all(
    const float* __restrict__ Wq, const float* __restrict__ Wk,
    const float* __restrict__ Wv, const float* __restrict__ Wo,
    const float* __restrict__ q, const float* __restrict__ kv,
    short* __restrict__ Wq_t, short* __restrict__ Wkv_t, short* __restrict__ Wo_t,
    short* __restrict__ qb, short* __restrict__ kvb) {
    __shared__ short Ts[64][65];
    int blk = blockIdx.x;
    if (blk < 256) {
        int c4 = threadIdx.x & 63, r4 = threadIdx.x >> 6;
        if (blk < 64) {                       // Wq (group-sum over g)
            int h = blk & 3, ib = blk >> 2;
#pragma unroll 4
            for (int jj = 0; jj < 16; ++jj) {
                int il = r4 * 16 + jj;
                float s = 0.f;
#pragma unroll
                for (int g = 0; g < 4; ++g)
                    s += Wq[(ib * 64 + il) * 1024 + (h * 4 + g) * 64 + c4];
                Ts[il][c4] = f2b(s);
            }
            __syncthreads();
#pragma unroll 4
            for (int jj = 0; jj < 16; ++jj) {
                int dl = r4 * 16 + jj;
                Wq_t[(h * 64 + dl) * 1024 + ib * 64 + c4] = Ts[c4][dl];
            }
        } else if (blk < 192) {               // Wk / Wv
            int t = blk - 64, ss = t >> 6; t &= 63;
            int ib = t >> 2, nb = t & 3;
            const float* W = ss ? Wv : Wk;
#pragma unroll 4
            for (int jj = 0; jj < 16; ++jj) {
                int il = r4 * 16 + jj;
                Ts[il][c4] = f2b(W[(ib * 64 + il) * 256 + nb * 64 + c4]);
            }
            __syncthreads();
#pragma unroll 4
            for (int jj = 0; jj < 16; ++jj) {
                int dl = r4 * 16 + jj;
                Wkv_t[(ss * 256 + nb * 64 + dl) * 1024 + ib * 64 + c4] = Ts[c4][dl];
            }
        } else {                              // Wo
            int t = blk - 192, kb = t >> 4, nb = t & 15;
#pragma unroll 4
            for (int jj = 0; jj < 16; ++jj) {
                int il = r4 * 16 + jj;
                Ts[il][c4] = f2b(Wo[(kb * 64 + il) * 1024 + nb * 64 + c4]);
            }
            __syncthreads();
#pragma unroll 4
            for (int jj = 0; jj < 16; ++jj) {
                int dl = r4 * 16 + jj;
                Wo_t[(nb * 64 + dl) * 256 + kb * 64 + c4] = Ts[c4][dl];
            }
        }
    } else if (blk < 2304) {
        long e = ((long)(blk - 256) * 256 + threadIdx.x) * 16;
        *(short8*)(qb + e)     = cvt8(q + e);
        *(short8*)(qb + e + 8) = cvt8(q + e + 8);
    } else {
        long e = ((long)(blk - 2304) * 256 + threadIdx.x) * 16;
        *(short8*)(kvb + e)     = cvt8(kv + e);
        *(short8*)(kvb + e + 8) = cvt8(kv + e + 8);
    }
}

// ---------------------------------------------------------------------------
// Projection GEMM, 128x64 tile, BK=64 (16 K-steps), 2-phase double-buffered,
// XOR-chunk-swizzled LDS (rule-21 both-sides). 768 blocks -> 3 blocks/CU;
// chunked XCD swizzle for L2 reuse. (R9 best configuration.)
template <int MODE>
__device__ __forceinline__ void gemm64(
    const short* __restrict__ A, const short* __restrict__ Wt,
    int m0, int n0, short* As, short* Bs,
    const int* __restrict__ coords, short* __restrict__ ropeDst,
    short* __restrict__ vDst) {
    const int t = threadIdx.x;
    const int w = t >> 6, lane = t & 63, ln = lane & 15, quad = lane >> 4;
    const int srow8 = lane >> 3;                    // 8 rows per inst
    const int schk = (lane & 7) ^ (srow8 & 7);      // pre-swizzled 16B chunk
    const int ln7 = ln & 7;
    floatx4 acc[2][4];
#pragma unroll
    for (int mt = 0; mt < 2; ++mt)
#pragma unroll
        for (int nt = 0; nt < 4; ++nt) acc[mt][nt] = floatx4{0.f, 0.f, 0.f, 0.f};

    auto stage = [&](int ks, int sel) {
#pragma unroll
        for (int i = 0; i < 4; ++i)               // A: 128 rows (wave: 32)
            __builtin_amdgcn_global_load_lds(
                (const void*)(A + (long)(m0 + w * 32 + i * 8 + srow8) * 1024 + ks + schk * 8),
                (void*)(As + sel * 8192 + (w * 32 + i * 8) * 64), 16, 0, 0);
#pragma unroll
        for (int i = 0; i < 2; ++i)               // B: 64 rows (wave: 16)
            __builtin_amdgcn_global_load_lds(
                (const void*)(Wt + (long)(n0 + w * 16 + i * 8 + srow8) * 1024 + ks + schk * 8),
                (void*)(Bs + sel * 4096 + (w * 16 + i * 8) * 64), 16, 0, 0);
    };

    stage(0, 0);
    __syncthreads();                           // drain prologue stage
    int cur = 0;
    for (int tt = 0; tt < 16; ++tt) {
        if (tt < 15) stage((tt + 1) * 64, cur ^ 1);   // prefetch next K-step
        const short* Ac = As + cur * 8192;
        const short* Bc = Bs + cur * 4096;
        short8 af[2][2], bf[4][2];
#pragma unroll
        for (int mt = 0; mt < 2; ++mt)
#pragma unroll
            for (int kc = 0; kc < 2; ++kc)
                af[mt][kc] = *(const short8*)(Ac + (w * 32 + mt * 16 + ln) * 64
                                              + ((kc * 4 + quad) ^ ln7) * 8);
#pragma unroll
        for (int nt = 0; nt < 4; ++nt)
#pragma unroll
            for (int kc = 0; kc < 2; ++kc)
                bf[nt][kc] = *(const short8*)(Bc + (nt * 16 + ln) * 64
                                              + ((kc * 4 + quad) ^ ln7) * 8);
#pragma unroll
        for (int kc = 0; kc < 2; ++kc)
#pragma unroll
            for (int mt = 0; mt < 2; ++mt)
#pragma unroll
                for (int nt = 0; nt < 4; ++nt)
                    acc[mt][nt] = MFMA32(af[mt][kc], bf[nt][kc], acc[mt][nt]);
        __syncthreads();                       // drains prefetch vmcnt + barrier
        cur ^= 1;
    }

    if (MODE == 1 || n0 < 256) {              // ---- rope path (Q or K)
        const int h = (n0 >> 6) & 3;
        const float scl = (MODE == 1) ? QSCL : 1.0f;
        const float L = -0.5756462732485114f; // -ln(1e4)/16
        const float fA = __expf((float)(ln >> 1) * L);
        const float fB = __expf((float)(8 + (ln >> 1)) * L);
        const float sgn = (ln & 1) ? 1.0f : -1.0f;
#pragma unroll
        for (int mt = 0; mt < 2; ++mt) {
            int row0 = m0 + w * 32 + mt * 16 + quad * 4;
#pragma unroll
            for (int r = 0; r < 4; ++r) {
                int row = row0 + r;
                float c0 = (float)coords[row * 2];
                float c1 = (float)coords[row * 2 + 1];
                float snv[4], csv[4];
                __sincosf(c0 * fA, &snv[0], &csv[0]);   // nt=0: axis0, j=ln>>1
                __sincosf(c0 * fB, &snv[1], &csv[1]);   // nt=1: axis0, j=8+ln>>1
                __sincosf(c1 * fA, &snv[2], &csv[2]);   // nt=2: axis1
                __sincosf(c1 * fB, &snv[3], &csv[3]);   // nt=3: axis1
                long rbase = ((long)((row >> 11) * 4 + h) * 2048 + (row & 2047)) * 64;
#pragma unroll
                for (int nt = 0; nt < 4; ++nt) {
                    float v = acc[mt][nt][r];
                    float p = __shfl_xor(v, 1, 64);     // pair partner (dd^1)
                    float o = v * (csv[nt] * scl) + p * (snv[nt] * (scl * sgn));
                    ropeDst[rbase + nt * 16 + ln] = f2b(o);
                }
            }
        }
    } else {                                  // ---- V transpose path
        const int h = ((n0 - 256) >> 6) & 3;
#pragma unroll
        for (int mt = 0; mt < 2; ++mt) {
            int row0 = m0 + w * 32 + mt * 16 + quad * 4;
            int b = row0 >> 11, s0 = row0 & 2047;
#pragma unroll
            for (int nt = 0; nt < 4; ++nt) {
                s4v ov;                       // 4 consecutive s per lane
#pragma unroll
                for (int r = 0; r < 4; ++r) ov[r] = f2b(acc[mt][nt][r]);
                *(s4v*)(vDst + (long)((b * 4 + h) * 64 + nt * 16 + ln) * 2048 + s0) = ov;
            }
        }
    }
}

__global__ __launch_bounds__(256, 3) void proj_gemm(
    const short* __restrict__ qb, const short* __restrict__ kvb,
    const short* __restrict__ Wq_t, const short* __restrict__ Wkv_t,
    const int* __restrict__ qc, const int* __restrict__ kvc,
    short* __restrict__ Qr, short* __restrict__ Kr, short* __restrict__ Vt) {
    __shared__ __align__(16) short As[2 * 8192];   // 32 KB A dbuf (128x64)
    __shared__ __align__(16) short Bs[2 * 4096];   // 16 KB B dbuf (64x64)
    // chunked XCD swizzle (768 = 8 x 96, bijective)
    int id = (blockIdx.x & 7) * 96 + (blockIdx.x >> 3);
    if (id < 256)
        gemm64<1>(qb, Wq_t, (id >> 2) * 128, (id & 3) * 64, As, Bs, qc, Qr, nullptr);
    else {
        int t2 = id - 256;
        gemm64<2>(kvb, Wkv_t, (t2 >> 3) * 128, (t2 & 7) * 64, As, Bs, kvc, Kr, Vt);
    }
}

// ---------------------------------------------------------------------------
// final GEMM: C[M][N] f32 = Ob[M][K] bf16 x Wo_t[N][K] bf16, 128x128 tile,
// BK=64 (4 K-steps), XOR-chunk-swizzled LDS. (R9, unchanged.)
__global__ __launch_bounds__(256, 2) void final_gemm(
    const short* __restrict__ Ob, const short* __restrict__ Wo_t, float* __restrict__ out) {
    __shared__ __align__(16) short As[2 * 8192];   // 32 KB (128x64)
    __shared__ __align__(16) short Bs[2 * 8192];   // 32 KB (128x64)
    const int m0 = blockIdx.x * 128, n0 = blockIdx.y * 128;
    const int tid = threadIdx.x;
    const int w = tid >> 6, lane = tid & 63, ln = lane & 15, quad = lane >> 4;
    const int wm = w >> 1, wn = w & 1;
    const int srow8 = lane >> 3;
    const int schk = (lane & 7) ^ (srow8 & 7);
    const int ln7 = ln & 7;
    floatx4 acc[4][4];
#pragma unroll
    for (int mt = 0; mt < 4; ++mt)
#pragma unroll
        for (int nt = 0; nt < 4; ++nt) acc[mt][nt] = floatx4{0.f, 0.f, 0.f, 0.f};

    auto stage = [&](int ks, int sel) {
#pragma unroll
        for (int i = 0; i < 4; ++i) {             // 128 rows each (wave: 32)
            __builtin_amdgcn_global_load_lds(
                (const void*)(Ob + (long)(m0 + w * 32 + i * 8 + srow8) * 256 + ks + schk * 8),
                (void*)(As + sel * 8192 + (w * 32 + i * 8) * 64), 16, 0, 0);
            __builtin_amdgcn_global_load_lds(
                (const void*)(Wo_t + (long)(n0 + w * 32 + i * 8 + srow8) * 256 + ks + schk * 8),
                (void*)(Bs + sel * 8192 + (w * 32 + i * 8) * 64), 16, 0, 0);
        }
    };
    stage(0, 0);
    __syncthreads();
    int cur = 0;
    for (int tt = 0; tt < 4; ++tt) {
        if (tt < 3) stage((tt + 1) * 64, cur ^ 1);
        const short* Ac = As + cur * 8192;
        const short* Bc = Bs + cur * 8192;
        short8 af[4][2], bf[4][2];
#pragma unroll
        for (int mt = 0; mt < 4; ++mt)
#pragma unroll
            for (int kc = 0; kc < 2; ++kc)
                af[mt][kc] = *(const short8*)(Ac + (wm * 64 + mt * 16 + ln) * 64
                                              + ((kc * 4 + quad) ^ ln7) * 8);
#pragma unroll
        for (int nt = 0; nt < 4; ++nt)
#pragma unroll
            for (int kc = 0; kc < 2; ++kc)
                bf[nt][kc] = *(const short8*)(Bc + (wn * 64 + nt * 16 + ln) * 64
                                              + ((kc * 4 + quad) ^ ln7) * 8);
#pragma unroll
        for (int kc = 0; kc < 2; ++kc)
#pragma unroll
            for (int mt = 0; mt < 4; ++mt)
#pragma unroll
                for (int nt = 0; nt < 4; ++nt)
                    acc[mt][nt] = MFMA32(af[mt][kc], bf[nt][kc], acc[mt][nt]);
        __syncthreads();
        cur ^= 1;
    }
#pragma unroll
    for (int mt = 0; mt < 4; ++mt) {
        int row0 = m0 + wm * 64 + mt * 16 + quad * 4;
#pragma unroll
        for (int nt = 0; nt < 4; ++nt) {
            int col = n0 + wn * 64 + nt * 16 + ln;
#pragma unroll
            for (int r = 0; r < 4; ++r)
                out[(long)(row0 + r) * 1024 + col] = acc[mt][nt][r];
        }
    }
}

// ---------------------------------------------------------------------------
// Flash attention, IN-BLOCK kv-split-2 (R6/R9 best): 512 threads = 8 waves.
// Waves 0-3 process kv[0:1024), waves 4-7 kv[1024:2048) on the SAME 64 q
// rows, each half with its own double-buffered K/V LDS (64 KB total -> 2
// blocks/CU = 16 waves/CU, grid 512 = one residency pass). Partials
// combined in-block via LDS; bf16 Ob store.
__global__ __launch_bounds__(512, 4) void attn_kernel(
    const short* __restrict__ Qr, const short* __restrict__ Kr,
    const short* __restrict__ Vt, short* __restrict__ Ob) {
    __shared__ __align__(16) short Kls[2][2][64 * 64];   // [half][buf][kv][d]
    __shared__ __align__(16) short Vls[2][2][64 * 64];   // [half][buf][d][kv]
    const int blk = blockIdx.x;
    const int x = blk & 7, y = blk >> 3;              // xcd-chunk swizzle
    const int bh = x * 2 + (y >> 5), qg = y & 31;
    const int w = threadIdx.x >> 6, lane = threadIdx.x & 63;
    const int qw = w & 3, half = w >> 2;
    const int ln = lane & 15, quad = lane >> 4;
    const int q0 = qg * 64 + qw * 16;
    const short* Qb = Qr + (long)bh * SEQKV * HD;
    const short* Kb = Kr + (long)bh * SEQKV * HD + (long)half * 1024 * HD;
    const short* Vb = Vt + (long)bh * HD * SEQKV + half * 1024;

    const int srow = lane >> 3;                       // 0..7 within 8-row group
    const int schk = (lane & 7) ^ (srow & 7);         // swizzled 16B chunk
    const long kstage0 = (long)(qw * 16 + srow) * HD + schk * 8;        // + kt*HD
    const long vstage0 = (long)(qw * 16 + srow) * SEQKV + schk * 8;     // + kt

    short8 qf[2];                              // B-frag of Q^T: [d-chunk32]
#pragma unroll
    for (int ck = 0; ck < 2; ++ck)
        qf[ck] = *(const short8*)(Qb + (long)(q0 + ln) * HD + ck * 32 + quad * 8);

    s4v ones;
#pragma unroll
    for (int j = 0; j < 4; ++j) ones[j] = (short)0x3F80;   // bf16 1.0

    floatx4 o[4], ol;
    ol = floatx4{0.f, 0.f, 0.f, 0.f};
#pragma unroll
    for (int nt = 0; nt < 4; ++nt) o[nt] = floatx4{0.f, 0.f, 0.f, 0.f};

    const int ln7 = ln & 7;
    int koff[2];
#pragma unroll
    for (int ck = 0; ck < 2; ++ck) koff[ck] = ln * 64 + ((ck * 4 + quad) ^ ln7) * 8;
    int voff[4];
#pragma unroll
    for (int t = 0; t < 4; ++t) voff[t] = ln * 64 + ((t * 2 + (quad >> 1)) ^ ln7) * 8 + (quad & 1) * 4;

#define STAGE(kt, sel)                                                                \
    do {                                                                              \
        _Pragma("unroll")                                                             \
        for (int i = 0; i < 2; ++i) {                                                 \
            __builtin_amdgcn_global_load_lds(                                         \
                (const void*)(Kb + (long)(kt) * HD + kstage0 + (long)i * 8 * HD),     \
                (void*)(&Kls[half][sel][(qw * 16 + i * 8) * 64]), 16, 0, 0);          \
            __builtin_amdgcn_global_load_lds(                                         \
                (const void*)(Vb + (kt) + vstage0 + (long)i * 8 * SEQKV),             \
                (void*)(&Vls[half][sel][(qw * 16 + i * 8) * 64]), 16, 0, 0);          \
        }                                                                             \
    } while (0)

    STAGE(0, 0);
    __syncthreads();
    int cur = 0;
    for (int tt = 0; tt < 16; ++tt) {
        if (tt < 15) STAGE((tt + 1) * 64, cur ^ 1);
        const short* Kc = &Kls[half][cur][0];
        const short* Vc = &Vls[half][cur][0];
#pragma unroll
        for (int t = 0; t < 4; ++t) {
            short8 a0 = *(const short8*)(Kc + t * 1024 + koff[0]);
            short8 a1 = *(const short8*)(Kc + t * 1024 + koff[1]);
            floatx4 st = {0.f, 0.f, 0.f, 0.f};
            __builtin_amdgcn_s_setprio(1);
            st = MFMA32(a0, qf[0], st);
            st = MFMA32(a1, qf[1], st);
            __builtin_amdgcn_s_setprio(0);
            float e0 = EXP2(st[0]), e1 = EXP2(st[1]), e2 = EXP2(st[2]), e3 = EXP2(st[3]);
            unsigned p0, p1;
            asm("v_cvt_pk_bf16_f32 %0, %1, %2" : "=v"(p0) : "v"(e0), "v"(e1));
            asm("v_cvt_pk_bf16_f32 %0, %1, %2" : "=v"(p1) : "v"(e2), "v"(e3));
            s4v pt;
            { unsigned tmp[2] = {p0, p1}; __builtin_memcpy(&pt, tmp, 8); }
            __builtin_amdgcn_s_setprio(1);
#pragma unroll
            for (int nt = 0; nt < 4; ++nt) {   // O^T += V^T P^T
                s4v vf = *(const s4v*)(Vc + nt * 1024 + voff[t]);
                o[nt] = MFMA16(vf, pt, o[nt]);
            }
            ol = MFMA16(ones, pt, ol);         // l += 1^T P^T
            __builtin_amdgcn_s_setprio(0);
        }
        __syncthreads();                       // drains prefetch vmcnt + barrier
        cur ^= 1;
    }
#undef STAGE
    // in-block combine (last loop barrier guarantees all LDS reads done):
    // half 1 publishes O (16 f32) + l per lane into Kls-scratch, half 0 reduces.
    float* cb = (float*)&Kls[0][0][0];             // 20 KB scratch, 16B-aligned slots
    const int slot = (qw * 64 + lane) * 20;        // 80 B stride (16B-multiple)
    if (half == 1) {
#pragma unroll
        for (int nt = 0; nt < 4; ++nt)
            *(floatx4*)(cb + slot + nt * 4) = o[nt];
        cb[slot + 16] = ol[0];
    }
    __syncthreads();
    if (half == 0) {
        const int b = bh >> 2, h = bh & 3;
        const float li = 1.0f / (ol[0] + cb[slot + 16]);
        const long base = ((long)(b * 2048 + q0 + ln)) * 256 + h * 64;
#pragma unroll
        for (int nt = 0; nt < 4; ++nt) {
            floatx4 o2 = *(const floatx4*)(cb + slot + nt * 4);
            s4v ov;
#pragma unroll
            for (int r = 0; r < 4; ++r) ov[r] = f2b((o[nt][r] + o2[r]) * li);
            *(s4v*)(Ob + base + nt * 16 + quad * 4) = ov;
        }
    }
}

// ---------------------------------------------------------------------------
extern "C" void kernel_launch(void* const* d_in, const int* in_sizes, int n_in,
                              void* d_out, int out_size, void* d_ws, size_t ws_size,
                              hipStream_t stream) {
    const float* q   = (const float*)d_in[0];
    const int*   qc  = (const int*)d_in[1];
    const float* kv  = (const float*)d_in[2];
    const int*   kvc = (const int*)d_in[3];
    const float* Wq  = (const float*)d_in[4];
    const float* Wk  = (const float*)d_in[5];
    const float* Wv  = (const float*)d_in[6];
    const float* Wo  = (const float*)d_in[7];
    float* out = (float*)d_out;

    char* ws = (char*)d_ws;
    const size_t MB = 1024 * 1024;
    short* Wq_t  = (short*)(ws);                 // 0.5 MB  [256][1024]
    short* Wkv_t = (short*)(ws + MB / 2);        // 1.0 MB  [512][1024]
    short* Wo_t  = (short*)(ws + 3 * MB / 2);    // 0.5 MB  [1024][256]
    short* qb    = (short*)(ws + 2 * MB);        // 16 MB   [8192][1024] bf16
    short* kvb   = (short*)(ws + 18 * MB);       // 16 MB
    short* Qr    = (short*)(ws + 34 * MB);       // 4 MB  [16][2048][64]
    short* Kr    = (short*)(ws + 38 * MB);       // 4 MB
    short* Vt    = (short*)(ws + 42 * MB);       // 4 MB  [16][64][2048]
    short* Ob    = (short*)(ws + 46 * MB);       // 4 MB  [8192][256]

    hipLaunchKernelGGL(prep_all, dim3(4352), dim3(256), 0, stream,
                       Wq, Wk, Wv, Wo, q, kv, Wq_t, Wkv_t, Wo_t, qb, kvb);
    hipLaunchKernelGGL(proj_gemm, dim3(768), dim3(256), 0, stream,
                       qb, kvb, Wq_t, Wkv_t, qc, kvc, Qr, Kr, Vt);
    hipLaunchKernelGGL(attn_kernel, dim3(512), dim3(512), 0, stream,
                       Qr, Kr, Vt, Ob);
    hipLaunchKernelGGL(final_gemm, dim3(64, 8), dim3(256), 0, stream, Ob, Wo_t, out);
}